// Round 9
// baseline (46.602 us; speedup 1.0000x reference)
//
#include <hip/hip_runtime.h>
#include <math.h>

#define BS 8
#define NF 32
#define NLOC 65536
#define DELTA_VAR 0.5f
#define DELTA_DIST 1.5f
#define GAMMA 1e-4f
#define G2 64        // k_var blocks per batch
#define CHUNK2 1024  // NLOC / G2

// ws float layout
#define WS_CNT0   0     // [BS] count of label==0 (pad to 16)
#define WS_SUMS   16    // [BS][NF][2] {sx, s0} = 512
#define WS_VARSUM 528   // [BS][2], each slot on its own 128B line (*32) = 512
#define WS_LABELS 1040  // u8 [BS][NLOC]

// ======== Kernel A: one block per (feature-row, batch) ====================
// Block (f,b): streams input row (b,f) fully contiguously (256KB), target
// row0 (L2-hot, shared by the batch's 32 blocks). Computes sx=sum(x),
// s0=sum(x*t0); block f also writes label slice [f*2048, (f+1)*2048).
__global__ __launch_bounds__(1024) void k_sums(const float* __restrict__ inp,
                                               const float* __restrict__ tgt,
                                               float* __restrict__ ws,
                                               unsigned char* __restrict__ labels) {
  const int f = blockIdx.x;  // 0..31
  const int b = blockIdx.y;  // 0..7
  const int tid = threadIdx.x;
  const int lane = tid & 63;
  const int wave = tid >> 6;  // 0..15
  const float* row = inp + ((size_t)b * NF + f) * NLOC;
  const float* trow = tgt + (size_t)b * 4 * NLOC;  // one-hot row 0

  float sx = 0.f, s0 = 0.f, cnt = 0.f;
#pragma unroll
  for (int it = 0; it < NLOC / 4096; ++it) {  // 16 iters
    const int n = it * 4096 + tid * 4;
    float4 x = *reinterpret_cast<const float4*>(row + n);
    float4 t = *reinterpret_cast<const float4*>(trow + n);
    sx += x.x + x.y + x.z + x.w;
    s0 += x.x * t.x + x.y * t.y + x.z * t.z + x.w * t.w;
    if (f == 0) cnt += t.x + t.y + t.z + t.w;
  }

  // balanced label slice: 2048 labels per block, re-read of L1/L2-hot target
  if (tid < 512) {
    const int n = f * 2048 + tid * 4;
    float4 t = *reinterpret_cast<const float4*>(trow + n);
    uchar4 l4;
    l4.x = t.x > 0.5f ? 0 : 1;
    l4.y = t.y > 0.5f ? 0 : 1;
    l4.z = t.z > 0.5f ? 0 : 1;
    l4.w = t.w > 0.5f ? 0 : 1;
    *reinterpret_cast<uchar4*>(labels + (size_t)b * NLOC + n) = l4;
  }

  // block reduce (sx, s0[, cnt])
  __shared__ float red[16][3];
#pragma unroll
  for (int m = 32; m >= 1; m >>= 1) {
    sx += __shfl_xor(sx, m, 64);
    s0 += __shfl_xor(s0, m, 64);
  }
  if (f == 0) {
#pragma unroll
    for (int m = 32; m >= 1; m >>= 1) cnt += __shfl_xor(cnt, m, 64);
  }
  if (lane == 0) {
    red[wave][0] = sx;
    red[wave][1] = s0;
    red[wave][2] = cnt;
  }
  __syncthreads();
  if (tid == 0) {
    float SX = 0.f, S0 = 0.f, C = 0.f;
#pragma unroll
    for (int w = 0; w < 16; ++w) {
      SX += red[w][0];
      S0 += red[w][1];
      C += red[w][2];
    }
    ws[WS_SUMS + ((size_t)b * NF + f) * 2 + 0] = SX;
    ws[WS_SUMS + ((size_t)b * NF + f) * 2 + 1] = S0;
    if (f == 0) ws[WS_CNT0 + b] = C;
  }
  if (f == 0 && tid < 2) ws[WS_VARSUM + (b * 2 + tid) * 32] = 0.f;
}

// ======== Kernel B: direct means + float4 var pass (R6-proven body) =======
__global__ __launch_bounds__(256, 4) void k_var(const float* __restrict__ inp,
                                                const unsigned char* __restrict__ labels,
                                                float* __restrict__ ws) {
  const int b = blockIdx.y;
  const int gx = blockIdx.x;
  const int tid = threadIdx.x;
  const int lane = tid & 63;
  const int fg = tid >> 6;

  __shared__ float2 m_lds[NF];
  __shared__ float vred[4][2];

  // means directly from the already-reduced sums (64 floats, L2-hot)
  if (tid < 32) {
    const float c0 = ws[WS_CNT0 + b];
    const float c1 = (float)NLOC - c0;
    const float sx = ws[WS_SUMS + ((size_t)b * NF + tid) * 2 + 0];
    const float s0 = ws[WS_SUMS + ((size_t)b * NF + tid) * 2 + 1];
    const float m0 = c0 > 0.f ? s0 / c0 : 0.f;
    const float m1 = c1 > 0.f ? (sx - s0) / c1 : 0.f;
    m_lds[tid] = make_float2(m0, m1);
  }
  __syncthreads();

  const float* inp_b = inp + (size_t)b * NF * NLOC;
  const int n = gx * CHUNK2 + tid * 4;
  const uchar4 lab = *reinterpret_cast<const uchar4*>(labels + (size_t)b * NLOC + n);
  float a0 = 0.f, a1 = 0.f, a2 = 0.f, a3 = 0.f;
#pragma unroll
  for (int f = 0; f < NF; ++f) {
    float4 x = *reinterpret_cast<const float4*>(inp_b + f * NLOC + n);
    float2 m = m_lds[f];
    float m0 = lab.x ? m.y : m.x;
    float m1 = lab.y ? m.y : m.x;
    float m2 = lab.z ? m.y : m.x;
    float m3 = lab.w ? m.y : m.x;
    float d0 = x.x - m0, d1 = x.y - m1, d2 = x.z - m2, d3 = x.w - m3;
    a0 += d0 * d0;
    a1 += d1 * d1;
    a2 += d2 * d2;
    a3 += d3 * d3;
  }
  float v0 = fmaxf(sqrtf(a0) - DELTA_VAR, 0.f);
  float v1 = fmaxf(sqrtf(a1) - DELTA_VAR, 0.f);
  float v2 = fmaxf(sqrtf(a2) - DELTA_VAR, 0.f);
  float v3 = fmaxf(sqrtf(a3) - DELTA_VAR, 0.f);
  v0 *= v0; v1 *= v1; v2 *= v2; v3 *= v3;
  float vacc0 = (lab.x ? 0.f : v0) + (lab.y ? 0.f : v1) +
                (lab.z ? 0.f : v2) + (lab.w ? 0.f : v3);
  float vacc1 = (lab.x ? v0 : 0.f) + (lab.y ? v1 : 0.f) +
                (lab.z ? v2 : 0.f) + (lab.w ? v3 : 0.f);

  float aa = __shfl_xor(vacc0, 32, 64);
  float bb = __shfl_xor(vacc1, 32, 64);
  float u = (lane & 32) ? (vacc1 + bb) : (vacc0 + aa);
  u += __shfl_xor(u, 16, 64);
  u += __shfl_xor(u, 8, 64);
  u += __shfl_xor(u, 4, 64);
  u += __shfl_xor(u, 2, 64);
  u += __shfl_xor(u, 1, 64);
  if ((lane & 31) == 0) vred[fg][lane >> 5] = u;
  __syncthreads();
  if (tid < 2) {
    float s = vred[0][tid] + vred[1][tid] + vred[2][tid] + vred[3][tid];
    atomicAdd(&ws[WS_VARSUM + (b * 2 + tid) * 32], s);
  }
}

// ======== Kernel C: epilogue (means recomputed from sums) =================
__global__ void k_final(const float* __restrict__ ws,
                        const int* __restrict__ ncl,
                        float* __restrict__ out) {
  const int tid = threadIdx.x;
  float total = 0.f;
  if (tid < BS) {
    const int b = tid;
    const float nc = (float)ncl[b];
    const float c0 = ws[WS_CNT0 + b];
    const float c1 = (float)NLOC - c0;
    float v0 = ws[WS_VARSUM + (b * 2 + 0) * 32];
    float v1 = ws[WS_VARSUM + (b * 2 + 1) * 32];
    float sv = (c0 > 0.f ? v0 / c0 : 0.f) + (c1 > 0.f ? v1 / c1 : 0.f);
    float l_var = sv / nc;
    float d2 = 0.f, n0s = 0.f, n1s = 0.f;
    for (int f = 0; f < NF; ++f) {
      float sx = ws[WS_SUMS + ((size_t)b * NF + f) * 2 + 0];
      float s0 = ws[WS_SUMS + ((size_t)b * NF + f) * 2 + 1];
      float m0 = c0 > 0.f ? s0 / c0 : 0.f;
      float m1 = c1 > 0.f ? (sx - s0) / c1 : 0.f;
      float df = m0 - m1;
      d2 += df * df;
      n0s += m0 * m0;
      n1s += m1 * m1;
    }
    float dn = d2 > 0.f ? sqrtf(d2) : 0.f;
    float h = fmaxf(2.f * DELTA_DIST - dn, 0.f);
    float l_dist = 2.f * h * h / (2.f * nc * (nc - 1.f));
    float r0 = n0s > 0.f ? sqrtf(n0s) : 0.f;
    float r1 = n1s > 0.f ? sqrtf(n1s) : 0.f;
    float l_reg = 0.5f * (r0 + r1);
    total = l_var + l_dist + GAMMA * l_reg;
  }
#pragma unroll
  for (int m = 1; m < 8; m <<= 1) total += __shfl_xor(total, m, 64);
  if (tid == 0) out[0] = total / (float)BS;
}

extern "C" void kernel_launch(void* const* d_in, const int* in_sizes, int n_in,
                              void* d_out, int out_size, void* d_ws, size_t ws_size,
                              hipStream_t stream) {
  const float* inp = (const float*)d_in[0];
  const float* tgt = (const float*)d_in[1];
  const int* ncl = (const int*)d_in[2];
  float* out = (float*)d_out;
  float* ws = (float*)d_ws;
  unsigned char* labels = (unsigned char*)(ws + WS_LABELS);

  k_sums<<<dim3(NF, BS), 1024, 0, stream>>>(inp, tgt, ws, labels);
  k_var<<<dim3(G2, BS), 256, 0, stream>>>(inp, labels, ws);
  k_final<<<1, 64, 0, stream>>>(ws, ncl, out);
}

// Round 10
// 33.611 us; speedup vs baseline: 1.3865x; 1.3865x over previous
//
#include <hip/hip_runtime.h>
#include <math.h>

#define BS 8
#define NF 32
#define NLOC 65536
#define DELTA_VAR 0.5f
#define DELTA_DIST 1.5f
#define GAMMA 1e-4f
#define G 128       // k_sums blocks per batch
#define CHUNK 512   // NLOC / G
#define G2 64       // k_var blocks per batch
#define CHUNK2 1024 // NLOC / G2

// ws float layout
#define WS_CTR    0     // [BS] u32 done-counters, one 128B line apart (b*32)
#define WS_VARSUM 528   // [BS][2], each slot on its own 128B line (*32) = 512
#define WS_PART   1040  // [BS][G][68]: 64 (f x {sx,s0}) + cnt0 (+3 pad)
#define WS_LABELS (1040 + BS * G * 68)  // u8 [BS][NLOC] after partials

// ======== Kernel A: partial sums + labels (R6-validated, 34.1us config) ===
// 256 threads = 4 waves; wave fg owns features fg*8..fg*8+7. Also zeroes
// varsum/counters/out for kernel B (kernel boundary = visibility/flush).
__global__ __launch_bounds__(256, 4) void k_sums(const float* __restrict__ inp,
                                                 const float* __restrict__ tgt,
                                                 float* __restrict__ ws,
                                                 unsigned char* __restrict__ labels,
                                                 float* __restrict__ out) {
  float* part = ws + WS_PART;
  const int b = blockIdx.y;
  const int gx = blockIdx.x;
  const int tid = threadIdx.x;
  const int lane = tid & 63;
  const int fg = tid >> 6;
  const int n0 = gx * CHUNK;
  const float* inp_b = inp + (size_t)b * NF * NLOC + (size_t)fg * 8 * NLOC;
  const float* t0_b = tgt + (size_t)b * 4 * NLOC;  // one-hot row 0

  float r[16];  // r[i*2]=sx_i, r[i*2+1]=s0_i
#pragma unroll
  for (int k = 0; k < 16; ++k) r[k] = 0.f;
  float cnt0 = 0.f;

#pragma unroll
  for (int it = 0; it < CHUNK / 256; ++it) {
    const int n = n0 + it * 256 + lane * 4;
    float4 t0 = *reinterpret_cast<const float4*>(t0_b + n);
    float4 x[8];
#pragma unroll
    for (int i = 0; i < 8; ++i)
      x[i] = *reinterpret_cast<const float4*>(inp_b + i * NLOC + n);
    if (fg == 0) {
      cnt0 += t0.x + t0.y + t0.z + t0.w;
      uchar4 l4;
      l4.x = t0.x > 0.5f ? 0 : 1;
      l4.y = t0.y > 0.5f ? 0 : 1;
      l4.z = t0.z > 0.5f ? 0 : 1;
      l4.w = t0.w > 0.5f ? 0 : 1;
      *reinterpret_cast<uchar4*>(labels + (size_t)b * NLOC + n) = l4;
    }
#pragma unroll
    for (int i = 0; i < 8; ++i) {
      r[i * 2 + 0] += x[i].x + x[i].y + x[i].z + x[i].w;
      r[i * 2 + 1] += x[i].x * t0.x + x[i].y * t0.y + x[i].z * t0.z + x[i].w * t0.w;
    }
  }

#define BSTEP(m, half)                                      \
  {                                                         \
    _Pragma("unroll") for (int j = 0; j < half; ++j) {      \
      float aa = __shfl_xor(r[j], m, 64);                   \
      float bb = __shfl_xor(r[j + half], m, 64);            \
      r[j] = (lane & m) ? (r[j + half] + bb) : (r[j] + aa); \
    }                                                       \
  }
  BSTEP(32, 8)
  BSTEP(16, 4)
  BSTEP(8, 2)
  BSTEP(4, 1)
#undef BSTEP
  r[0] += __shfl_xor(r[0], 2, 64);
  r[0] += __shfl_xor(r[0], 1, 64);

  __shared__ float pp[68];
  if ((lane & 3) == 0) pp[fg * 16 + (lane >> 2)] = r[0];

  if (fg == 0) {
    cnt0 += __shfl_xor(cnt0, 32, 64);
    cnt0 += __shfl_xor(cnt0, 16, 64);
    cnt0 += __shfl_xor(cnt0, 8, 64);
    cnt0 += __shfl_xor(cnt0, 4, 64);
    cnt0 += __shfl_xor(cnt0, 2, 64);
    cnt0 += __shfl_xor(cnt0, 1, 64);
    if (lane == 0) pp[64] = cnt0;
  }
  __syncthreads();
  if (tid < 65) part[((size_t)(b * G + gx)) * 68 + tid] = pp[tid];
  if (gx == 0) {
    if (tid < 2) ws[WS_VARSUM + (b * 2 + tid) * 32] = 0.f;
    if (tid == 2) *reinterpret_cast<unsigned int*>(ws + WS_CTR + b * 32) = 0u;
    if (b == 0 && tid == 3) out[0] = 0.f;
  }
}

// ======== Kernel B: means-reduce + float4 var pass + last-block epilogue ==
__global__ __launch_bounds__(256, 4) void k_var(const float* __restrict__ inp,
                                                const unsigned char* __restrict__ labels,
                                                const int* __restrict__ ncl,
                                                float* __restrict__ ws,
                                                float* __restrict__ out) {
  const int b = blockIdx.y;
  const int gx = blockIdx.x;
  const int tid = threadIdx.x;
  const int lane = tid & 63;
  const int fg = tid >> 6;

  __shared__ float sbuf[4][64];
  __shared__ float tbuf[64];
  __shared__ float cbuf[G];
  __shared__ float cnt_s[2];
  __shared__ float2 m_lds[NF];
  __shared__ float vred[4][2];

  // ---- Phase 1: reduce own batch's partials -> means in LDS (R6 body) ----
  {
    const float* pb = ws + WS_PART + (size_t)b * G * 68;
    const int q = tid >> 6, rem = tid & 63;
    float s = 0.f;
    for (int g2 = q * 32; g2 < q * 32 + 32; ++g2) s += pb[(size_t)g2 * 68 + rem];
    sbuf[q][rem] = s;
    if (tid < G) cbuf[tid] = pb[(size_t)tid * 68 + 64];
    __syncthreads();
    if (tid < 64) {
      tbuf[tid] = sbuf[0][tid] + sbuf[1][tid] + sbuf[2][tid] + sbuf[3][tid];
      float c = cbuf[tid] + cbuf[tid + 64];
      c += __shfl_xor(c, 32, 64);
      c += __shfl_xor(c, 16, 64);
      c += __shfl_xor(c, 8, 64);
      c += __shfl_xor(c, 4, 64);
      c += __shfl_xor(c, 2, 64);
      c += __shfl_xor(c, 1, 64);
      if (tid == 0) {
        cnt_s[0] = c;
        cnt_s[1] = (float)NLOC - c;
      }
    }
    __syncthreads();
    if (tid < 32) {
      const int f = tid;
      float sx = tbuf[f * 2], s0 = tbuf[f * 2 + 1];
      float c0 = cnt_s[0], c1 = cnt_s[1];
      float m0 = c0 > 0.f ? s0 / c0 : 0.f;
      float m1 = c1 > 0.f ? (sx - s0) / c1 : 0.f;
      m_lds[f] = make_float2(m0, m1);
    }
    __syncthreads();
  }

  // ---- Phase 2: var pass, float4/thread (R6 body) ----
  {
    const float* inp_b = inp + (size_t)b * NF * NLOC;
    const int n = gx * CHUNK2 + tid * 4;
    const uchar4 lab = *reinterpret_cast<const uchar4*>(labels + (size_t)b * NLOC + n);
    float a0 = 0.f, a1 = 0.f, a2 = 0.f, a3 = 0.f;
#pragma unroll
    for (int f = 0; f < NF; ++f) {
      float4 x = *reinterpret_cast<const float4*>(inp_b + f * NLOC + n);
      float2 m = m_lds[f];
      float m0 = lab.x ? m.y : m.x;
      float m1 = lab.y ? m.y : m.x;
      float m2 = lab.z ? m.y : m.x;
      float m3 = lab.w ? m.y : m.x;
      float d0 = x.x - m0, d1 = x.y - m1, d2 = x.z - m2, d3 = x.w - m3;
      a0 += d0 * d0;
      a1 += d1 * d1;
      a2 += d2 * d2;
      a3 += d3 * d3;
    }
    float v0 = fmaxf(sqrtf(a0) - DELTA_VAR, 0.f);
    float v1 = fmaxf(sqrtf(a1) - DELTA_VAR, 0.f);
    float v2 = fmaxf(sqrtf(a2) - DELTA_VAR, 0.f);
    float v3 = fmaxf(sqrtf(a3) - DELTA_VAR, 0.f);
    v0 *= v0; v1 *= v1; v2 *= v2; v3 *= v3;
    float vacc0 = (lab.x ? 0.f : v0) + (lab.y ? 0.f : v1) +
                  (lab.z ? 0.f : v2) + (lab.w ? 0.f : v3);
    float vacc1 = (lab.x ? v0 : 0.f) + (lab.y ? v1 : 0.f) +
                  (lab.z ? v2 : 0.f) + (lab.w ? v3 : 0.f);

    float aa = __shfl_xor(vacc0, 32, 64);
    float bb = __shfl_xor(vacc1, 32, 64);
    float u = (lane & 32) ? (vacc1 + bb) : (vacc0 + aa);
    u += __shfl_xor(u, 16, 64);
    u += __shfl_xor(u, 8, 64);
    u += __shfl_xor(u, 4, 64);
    u += __shfl_xor(u, 2, 64);
    u += __shfl_xor(u, 1, 64);
    if ((lane & 31) == 0) vred[fg][lane >> 5] = u;
    __syncthreads();
    if (tid < 2) {
      float s = vred[0][tid] + vred[1][tid] + vred[2][tid] + vred[3][tid];
      atomicAdd(&ws[WS_VARSUM + (b * 2 + tid) * 32], s);
    }
  }

  // ---- Phase 3: last arriving block of this batch computes epilogue ----
  // The compiler's pre-barrier vmcnt(0) drain guarantees the varsum RMWs
  // above completed at the coherence point before the counter RMW below.
  __syncthreads();
  if (tid == 0) {
    unsigned int* ctr = reinterpret_cast<unsigned int*>(ws + WS_CTR + b * 32);
    unsigned int old = atomicAdd(ctr, 1u);
    if (old == (unsigned int)(G2 - 1)) {
      // coherent-point reads of varsum via RMW-with-zero
      float v0 = atomicAdd(&ws[WS_VARSUM + (b * 2 + 0) * 32], 0.f);
      float v1 = atomicAdd(&ws[WS_VARSUM + (b * 2 + 1) * 32], 0.f);
      const float nc = (float)ncl[b];
      float c0 = cnt_s[0], c1 = cnt_s[1];
      float l_var = ((c0 > 0.f ? v0 / c0 : 0.f) + (c1 > 0.f ? v1 / c1 : 0.f)) / nc;
      float d2 = 0.f, n0s = 0.f, n1s = 0.f;
      for (int f = 0; f < NF; ++f) {
        float2 m = m_lds[f];
        float df = m.x - m.y;
        d2 += df * df;
        n0s += m.x * m.x;
        n1s += m.y * m.y;
      }
      float dn = d2 > 0.f ? sqrtf(d2) : 0.f;
      float h = fmaxf(2.f * DELTA_DIST - dn, 0.f);
      float l_dist = 2.f * h * h / (2.f * nc * (nc - 1.f));
      float r0 = n0s > 0.f ? sqrtf(n0s) : 0.f;
      float r1 = n1s > 0.f ? sqrtf(n1s) : 0.f;
      float l_reg = 0.5f * (r0 + r1);
      atomicAdd(out, (l_var + l_dist + GAMMA * l_reg) / (float)BS);
    }
  }
}

extern "C" void kernel_launch(void* const* d_in, const int* in_sizes, int n_in,
                              void* d_out, int out_size, void* d_ws, size_t ws_size,
                              hipStream_t stream) {
  const float* inp = (const float*)d_in[0];
  const float* tgt = (const float*)d_in[1];
  const int* ncl = (const int*)d_in[2];
  float* out = (float*)d_out;
  float* ws = (float*)d_ws;
  unsigned char* labels = (unsigned char*)(ws + WS_LABELS);

  k_sums<<<dim3(G, BS), 256, 0, stream>>>(inp, tgt, ws, labels, out);
  k_var<<<dim3(G2, BS), 256, 0, stream>>>(inp, labels, ncl, ws, out);
}